// Round 3
// baseline (297.100 us; speedup 1.0000x reference)
//
#include <hip/hip_runtime.h>
#include <hip/hip_bf16.h>

typedef unsigned short u16;
typedef __attribute__((ext_vector_type(4))) float f32x4;
typedef __attribute__((ext_vector_type(8))) short short8;

#define BN_EPS 1e-5f

__device__ __forceinline__ u16 f2b(float x) {
  union { float f; unsigned int u; } v; v.f = x;
  unsigned int r = (v.u + 0x7FFFu + ((v.u >> 16) & 1u)) >> 16;
  return (u16)r;
}
__device__ __forceinline__ float b2f(u16 u) {
  union { unsigned int u; float f; } v; v.u = ((unsigned int)u) << 16;
  return v.f;
}

// ---------------------------------------------------------------------------
// prep: fold BN into alpha/beta; convert W1/W2 to bf16 in blocked [kt][o][32k]
// ---------------------------------------------------------------------------
__global__ void prep_kernel(const float* __restrict__ w1, const float* __restrict__ b1,
                            const float* __restrict__ g1, const float* __restrict__ be1,
                            const float* __restrict__ m1, const float* __restrict__ v1,
                            const float* __restrict__ w2, const float* __restrict__ b2,
                            const float* __restrict__ g2, const float* __restrict__ be2,
                            const float* __restrict__ m2, const float* __restrict__ v2,
                            u16* __restrict__ w1b, u16* __restrict__ w2b,
                            float* __restrict__ al1, float* __restrict__ bt1,
                            float* __restrict__ al2, float* __restrict__ bt2) {
  int t = threadIdx.x;
  int blk = blockIdx.x;
  if (blk < 384) {                       // w1: 256x384
    int id = blk * 256 + t;
    unsigned o = (unsigned)id / 384u;
    unsigned c = (unsigned)id % 384u;
    w1b[(c >> 5) * 8192 + o * 32 + (c & 31)] = f2b(w1[id]);
  } else if (blk < 640) {                // w2: 256x256
    int j = (blk - 384) * 256 + t;
    unsigned o = (unsigned)j >> 8;
    unsigned c = (unsigned)j & 255u;
    w2b[(c >> 5) * 8192 + o * 32 + (c & 31)] = f2b(w2[j]);
  } else if (blk == 640) {
    float a = g1[t] / sqrtf(v1[t] + BN_EPS);
    al1[t] = a;
    bt1[t] = (b1[t] - m1[t]) * a + be1[t];
  } else {
    float a = g2[t] / sqrtf(v2[t] + BN_EPS);
    al2[t] = a;
    bt2[t] = (b2[t] - m2[t]) * a + be2[t];
  }
}

// ---------------------------------------------------------------------------
// transpose features2 [B][256][2048] f32 -> f2t [B][2048][256] bf16
// ---------------------------------------------------------------------------
__global__ void transpose_f2_kernel(const float* __restrict__ f2, u16* __restrict__ f2t) {
  __shared__ float tile[32][33];
  int t = threadIdx.x;
  int tx = t & 31, ty = t >> 5;          // ty in [0,8)
  int b = blockIdx.z;
  int n2t = blockIdx.x * 32, ct = blockIdx.y * 32;
#pragma unroll
  for (int i = 0; i < 4; ++i) {
    int c = ct + ty + i * 8;
    tile[ty + i * 8][tx] = f2[((size_t)b * 256 + c) * 2048 + n2t + tx];
  }
  __syncthreads();
#pragma unroll
  for (int i = 0; i < 4; ++i) {
    int n2 = n2t + ty + i * 8;
    f2t[((size_t)b * 2048 + n2) * 256 + ct + tx] = f2b(tile[tx][ty + i * 8]);
  }
}

// ---------------------------------------------------------------------------
// knn + interp + skip-copy. One block = one batch x 128 query points.
// Phase 1: each LANE owns 4 queries (qg = t&31, q = qg+32i) and one slice of
// 256 candidates (s = t>>5) -> one ds_read_b128 feeds 4 (q,cand) pairs.
// Distance top-3 kept with med3-style updates (3 ops) + index cndmasks.
// xb blocked layout: [panel][kt(12)][n(64)][kc(32)] bf16; block = 2 panels.
// ---------------------------------------------------------------------------
__global__ __launch_bounds__(256) void knn_interp_kernel(
    const float* __restrict__ xyz1, const float* __restrict__ xyz2,
    const float* __restrict__ f1, const u16* __restrict__ f2t,
    u16* __restrict__ xb) {
  union Lds {
    struct { float4 pts[2048]; float md[8 * 128 * 3]; int mi[8 * 128 * 3]; } a;
    float f1t[128 * 129];
  };
  __shared__ Lds lds;
  __shared__ float wts[128 * 3];
  __shared__ int idxs[128 * 3];          // premultiplied by 256

  int t = threadIdx.x;
  int b = blockIdx.x >> 6;
  int n1_0 = (blockIdx.x & 63) * 128;
  int panel0 = blockIdx.x * 2;

  // phase 0: stage candidates (x,y,z,|x|^2)
  const float* x2 = xyz2 + b * 3 * 2048;
  for (int j = t; j < 2048; j += 256) {
    float cx = x2[j], cy = x2[2048 + j], cz = x2[4096 + j];
    float nsq = (cx * cx + cy * cy) + cz * cz;
    lds.a.pts[j] = make_float4(cx, cy, cz, nsq);
  }
  __syncthreads();

  // phase 1: 8 slices x 256 candidates; 4 queries per lane
  {
    int qg = t & 31, s = t >> 5;
    const float* x1 = xyz1 + b * 3 * 8192;
    float nx[4], ny[4], nz[4], nsq1[4];
    float d[4][3];
    int id[4][3];
#pragma unroll
    for (int i = 0; i < 4; ++i) {
      int n1 = n1_0 + qg + 32 * i;
      float bx = x1[n1], by = x1[8192 + n1], bz = x1[16384 + n1];
      nsq1[i] = (bx * bx + by * by) + bz * bz;
      nx[i] = -2.f * bx; ny[i] = -2.f * by; nz[i] = -2.f * bz;
      d[i][0] = d[i][1] = d[i][2] = 3.4e38f;
      id[i][0] = id[i][1] = id[i][2] = 0;
    }
    int jb = s * 256;
#pragma unroll 4
    for (int jj = 0; jj < 256; ++jj) {
      float4 c = lds.a.pts[jb + jj];
      int j = jb + jj;
#pragma unroll
      for (int i = 0; i < 4; ++i) {
        float sq = fmaf(nx[i], c.x, fmaf(ny[i], c.y, fmaf(nz[i], c.z, nsq1[i] + c.w)));
        bool c0 = sq < d[i][0], c1 = sq < d[i][1], c2 = sq < d[i][2];
        id[i][2] = c1 ? id[i][1] : (c2 ? j : id[i][2]);
        id[i][1] = c0 ? id[i][0] : (c1 ? j : id[i][1]);
        id[i][0] = c0 ? j : id[i][0];
        d[i][2] = fminf(fmaxf(sq, d[i][1]), d[i][2]);   // med3
        d[i][1] = fminf(fmaxf(sq, d[i][0]), d[i][1]);   // med3
        d[i][0] = fminf(sq, d[i][0]);
      }
    }
#pragma unroll
    for (int i = 0; i < 4; ++i) {
      int q = qg + 32 * i;
#pragma unroll
      for (int k = 0; k < 3; ++k) {
        lds.a.md[(s * 128 + q) * 3 + k] = d[i][k];
        lds.a.mi[(s * 128 + q) * 3 + k] = id[i][k];
      }
    }
  }
  __syncthreads();
  if (t < 128) {
    // merge slices s=0..7 in ascending-index order (preserves tie-break)
    float d0 = 3.4e38f, d1 = 3.4e38f, d2 = 3.4e38f;
    int i0 = 0, i1 = 0, i2 = 0;
#pragma unroll
    for (int s = 0; s < 8; ++s) {
#pragma unroll
      for (int k = 0; k < 3; ++k) {
        float dd = lds.a.md[(s * 128 + t) * 3 + k];
        int ii = lds.a.mi[(s * 128 + t) * 3 + k];
        bool c0 = dd < d0, c1 = dd < d1, c2 = dd < d2;
        i2 = c1 ? i1 : (c2 ? ii : i2);
        i1 = c0 ? i0 : (c1 ? ii : i1);
        i0 = c0 ? ii : i0;
        d2 = fminf(fmaxf(dd, d1), d2);
        d1 = fminf(fmaxf(dd, d0), d1);
        d0 = fminf(dd, d0);
      }
    }
    float e0 = fmaxf(d0, 1e-10f), e1 = fmaxf(d1, 1e-10f), e2 = fmaxf(d2, 1e-10f);
    float w0 = 1.0f / e0, w1 = 1.0f / e1, w2 = 1.0f / e2;
    float sm = (w0 + w1) + w2;
    wts[t * 3 + 0] = w0 / sm; wts[t * 3 + 1] = w1 / sm; wts[t * 3 + 2] = w2 / sm;
    idxs[t * 3 + 0] = i0 * 256; idxs[t * 3 + 1] = i1 * 256; idxs[t * 3 + 2] = i2 * 256;
  }
  __syncthreads();

  // phase 2: interp 256 channels (thread = channel), 128 queries, blocked write
  {
    const u16* f2tb = f2t + (size_t)b * 2048 * 256;
#pragma unroll 4
    for (int p = 0; p < 128; ++p) {
      int j0 = idxs[p * 3 + 0], j1 = idxs[p * 3 + 1], j2 = idxs[p * 3 + 2];
      float w0 = wts[p * 3 + 0], w1 = wts[p * 3 + 1], w2 = wts[p * 3 + 2];
      float v = (w0 * b2f(f2tb[j0 + t]) + w1 * b2f(f2tb[j1 + t]))
                + w2 * b2f(f2tb[j2 + t]);
      xb[(size_t)(panel0 + (p >> 6)) * 24576 + (size_t)((t >> 5) * 2048) +
         (p & 63) * 32 + (t & 31)] = f2b(v);
    }
  }
  __syncthreads();   // before aliasing lds.a with lds.f1t

  // phase 3: skip features (channels 256..383) via LDS transpose, 128 queries
  {
    const float* f1b = f1 + (size_t)b * 128 * 8192 + n1_0;
#pragma unroll 2
    for (int it = 0; it < 64; ++it) {
      int c = it * 2 + (t >> 7);
      int n = t & 127;
      lds.f1t[c * 129 + n] = f1b[(size_t)c * 8192 + n];
    }
    __syncthreads();
#pragma unroll 2
    for (int it = 0; it < 64; ++it) {
      int v = it * 256 + t;
      int c = v & 127, p = v >> 7;
      float val = lds.f1t[c * 129 + p];
      xb[(size_t)(panel0 + (p >> 6)) * 24576 + (size_t)(8 + (c >> 5)) * 2048 +
         (p & 63) * 32 + (c & 31)] = f2b(val);
    }
  }
}

// ---------------------------------------------------------------------------
// Streaming GEMM (no LDS in K-loop, no barriers) + coalesced LDS-repack
// epilogues. block: 256 threads (4 waves), tile 256(o) x 64(n), mfma
// 16x16x32 bf16.  A (weights) wb [kt][256o][32k]; B (acts) xin
// [panel][kt][64n][32k].  Dynamic LDS:
//   FINAL=false: u16 Y[512*40]   (rows oh*64+col, stride 40, 16B-aligned)
//   FINAL=true : f32 Y2[4][64*68] (per-wave 64o x 64col, stride 68)
// ---------------------------------------------------------------------------
template <int KT, bool FINAL>
__global__ __launch_bounds__(256, 2) void gemm_kernel(
    const u16* __restrict__ xin, const u16* __restrict__ wb,
    const float* __restrict__ alpha, const float* __restrict__ beta,
    u16* __restrict__ yout, float* __restrict__ fout) {
  extern __shared__ char elraw[];
  int t = threadIdx.x;
  int panel = blockIdx.x;
  int w = t >> 6, lane = t & 63, l15 = lane & 15, quad = lane >> 4;

  f32x4 acc[4][4];
#pragma unroll
  for (int m = 0; m < 4; ++m)
#pragma unroll
    for (int n = 0; n < 4; ++n)
      acc[m][n] = (f32x4){0.f, 0.f, 0.f, 0.f};

  const u16* aw = wb + (size_t)(w * 64 + l15) * 32 + quad * 8;
  const u16* bx = xin + (size_t)panel * (KT * 2048) + (size_t)l15 * 32 + quad * 8;

#pragma unroll 2
  for (int kt = 0; kt < KT; ++kt) {
    short8 af[4], bf[4];
#pragma unroll
    for (int m = 0; m < 4; ++m)
      af[m] = *(const short8*)(aw + kt * 8192 + m * 512);
#pragma unroll
    for (int n = 0; n < 4; ++n)
      bf[n] = *(const short8*)(bx + kt * 2048 + n * 512);
#pragma unroll
    for (int m = 0; m < 4; ++m)
#pragma unroll
      for (int n = 0; n < 4; ++n)
        acc[m][n] = __builtin_amdgcn_mfma_f32_16x16x32_bf16(af[m], bf[n], acc[m][n], 0, 0, 0);
  }

  float al[4][4], bt[4][4];
#pragma unroll
  for (int m = 0; m < 4; ++m)
#pragma unroll
    for (int r = 0; r < 4; ++r) {
      int o = w * 64 + m * 16 + quad * 4 + r;
      al[m][r] = alpha[o];
      bt[m][r] = beta[o];
    }

  if (FINAL) {
    // --- layer-2 epilogue: per-wave LDS repack -> 256B-contiguous f32 rows ---
    float* Y2 = (float*)elraw + w * (64 * 68);
#pragma unroll
    for (int m = 0; m < 4; ++m)
#pragma unroll
      for (int n = 0; n < 4; ++n)
#pragma unroll
        for (int r = 0; r < 4; ++r) {
          int ol = m * 16 + quad * 4 + r;
          int col = n * 16 + l15;
          Y2[ol * 68 + col] = fmaxf(fmaf(al[m][r], acc[m][n][r], bt[m][r]), 0.f);
        }
    __syncthreads();
    size_t obase = (size_t)(panel >> 7) * 2097152 + (size_t)((panel * 64) & 8191);
#pragma unroll
    for (int it = 0; it < 16; ++it) {
      int row = it * 4 + quad;           // o_local within wave
      int o = w * 64 + row;
      float4 vv = *(const float4*)&Y2[row * 68 + l15 * 4];
      *(float4*)(fout + obase + (size_t)o * 8192 + l15 * 4) = vv;
    }
  } else {
    // --- layer-1 epilogue: LDS repack -> fully linear 16B bf16 stores ---
    u16* Y = (u16*)elraw;
#pragma unroll
    for (int m = 0; m < 4; ++m) {
      int rowbase = (w * 2 + (m >> 1)) * 64;
      int osub = (m & 1) * 16 + quad * 4;
#pragma unroll
      for (int n = 0; n < 4; ++n) {
        int col = n * 16 + l15;
        ushort4 pk;
        pk.x = f2b(fmaxf(fmaf(al[m][0], acc[m][n][0], bt[m][0]), 0.f));
        pk.y = f2b(fmaxf(fmaf(al[m][1], acc[m][n][1], bt[m][1]), 0.f));
        pk.z = f2b(fmaxf(fmaf(al[m][2], acc[m][n][2], bt[m][2]), 0.f));
        pk.w = f2b(fmaxf(fmaf(al[m][3], acc[m][n][3], bt[m][3]), 0.f));
        *(ushort4*)&Y[(rowbase + col) * 40 + osub] = pk;
      }
    }
    __syncthreads();
    u16* yp = yout + (size_t)panel * 16384;
#pragma unroll
    for (int i = 0; i < 8; ++i) {
      int c2 = i * 256 + t;
      int row = c2 >> 2, part = c2 & 3;
      *(uint4*)(yp + row * 32 + part * 8) = *(const uint4*)&Y[row * 40 + part * 8];
    }
  }
}

// ---------------------------------------------------------------------------
// ws layout (bytes):
//   [0,          50331648)  xb   bf16 [1024 panels][12][64][32]   48 MB
//   [50331648,   83886080)  y1   bf16 [1024][8][64][32]           32 MB
//      (f2t bf16 8 MB aliases the start of y1 — dead before y1 is written)
//   [83886080,   84082688)  w1b  bf16 blocked
//   [84082688,   84213760)  w2b  bf16 blocked
//   [84213760,   84217856)  al1/bt1/al2/bt2 f32
// total ~80.3 MB
// ---------------------------------------------------------------------------
extern "C" void kernel_launch(void* const* d_in, const int* in_sizes, int n_in,
                              void* d_out, int out_size, void* d_ws, size_t ws_size,
                              hipStream_t stream) {
  const float* xyz1 = (const float*)d_in[0];
  const float* xyz2 = (const float*)d_in[1];
  const float* f1   = (const float*)d_in[2];
  const float* f2   = (const float*)d_in[3];
  const float* w1   = (const float*)d_in[4];
  const float* b1   = (const float*)d_in[5];
  const float* g1   = (const float*)d_in[6];
  const float* be1  = (const float*)d_in[7];
  const float* m1   = (const float*)d_in[8];
  const float* v1   = (const float*)d_in[9];
  const float* w2   = (const float*)d_in[10];
  const float* b2   = (const float*)d_in[11];
  const float* g2   = (const float*)d_in[12];
  const float* be2  = (const float*)d_in[13];
  const float* m2   = (const float*)d_in[14];
  const float* v2   = (const float*)d_in[15];

  char* ws = (char*)d_ws;
  u16* xb   = (u16*)(ws);
  u16* y1   = (u16*)(ws + 50331648);
  u16* f2t  = (u16*)(ws + 50331648);   // aliases y1 region; dead before y1 write
  u16* w1b  = (u16*)(ws + 83886080);
  u16* w2b  = (u16*)(ws + 84082688);
  float* al1 = (float*)(ws + 84213760);
  float* bt1 = (float*)(ws + 84214784);
  float* al2 = (float*)(ws + 84215808);
  float* bt2 = (float*)(ws + 84216832);
  float* out = (float*)d_out;

  prep_kernel<<<642, 256, 0, stream>>>(w1, b1, g1, be1, m1, v1,
                                       w2, b2, g2, be2, m2, v2,
                                       w1b, w2b, al1, bt1, al2, bt2);
  transpose_f2_kernel<<<dim3(64, 8, 8), 256, 0, stream>>>(f2, f2t);
  knn_interp_kernel<<<512, 256, 0, stream>>>(xyz1, xyz2, f1, f2t, xb);
  gemm_kernel<12, false><<<1024, 256, 512 * 40 * 2, stream>>>(xb, w1b, al1, bt1, y1, nullptr);
  gemm_kernel<8, true><<<1024, 256, 4 * 64 * 68 * 4, stream>>>(y1, w2b, al2, bt2, nullptr, out);
}

// Round 4
// 267.181 us; speedup vs baseline: 1.1120x; 1.1120x over previous
//
#include <hip/hip_runtime.h>
#include <hip/hip_bf16.h>

typedef unsigned short u16;
typedef __attribute__((ext_vector_type(4))) float f32x4;
typedef __attribute__((ext_vector_type(8))) short short8;

#define BN_EPS 1e-5f

__device__ __forceinline__ u16 f2b(float x) {
  union { float f; unsigned int u; } v; v.f = x;
  unsigned int r = (v.u + 0x7FFFu + ((v.u >> 16) & 1u)) >> 16;
  return (u16)r;
}
__device__ __forceinline__ float b2f(u16 u) {
  union { unsigned int u; float f; } v; v.u = ((unsigned int)u) << 16;
  return v.f;
}

// ---------------------------------------------------------------------------
// prep: fold BN into alpha/beta; convert W1/W2 to bf16 in blocked [kt][o][32k]
// ---------------------------------------------------------------------------
__global__ void prep_kernel(const float* __restrict__ w1, const float* __restrict__ b1,
                            const float* __restrict__ g1, const float* __restrict__ be1,
                            const float* __restrict__ m1, const float* __restrict__ v1,
                            const float* __restrict__ w2, const float* __restrict__ b2,
                            const float* __restrict__ g2, const float* __restrict__ be2,
                            const float* __restrict__ m2, const float* __restrict__ v2,
                            u16* __restrict__ w1b, u16* __restrict__ w2b,
                            float* __restrict__ al1, float* __restrict__ bt1,
                            float* __restrict__ al2, float* __restrict__ bt2) {
  int t = threadIdx.x;
  int blk = blockIdx.x;
  if (blk < 384) {                       // w1: 256x384
    int id = blk * 256 + t;
    unsigned o = (unsigned)id / 384u;
    unsigned c = (unsigned)id % 384u;
    w1b[(c >> 5) * 8192 + o * 32 + (c & 31)] = f2b(w1[id]);
  } else if (blk < 640) {                // w2: 256x256
    int j = (blk - 384) * 256 + t;
    unsigned o = (unsigned)j >> 8;
    unsigned c = (unsigned)j & 255u;
    w2b[(c >> 5) * 8192 + o * 32 + (c & 31)] = f2b(w2[j]);
  } else if (blk == 640) {
    float a = g1[t] / sqrtf(v1[t] + BN_EPS);
    al1[t] = a;
    bt1[t] = (b1[t] - m1[t]) * a + be1[t];
  } else {
    float a = g2[t] / sqrtf(v2[t] + BN_EPS);
    al2[t] = a;
    bt2[t] = (b2[t] - m2[t]) * a + be2[t];
  }
}

// ---------------------------------------------------------------------------
// transpose features2 [B][256][2048] f32 -> f2t [B][2048][256] bf16
// ---------------------------------------------------------------------------
__global__ void transpose_f2_kernel(const float* __restrict__ f2, u16* __restrict__ f2t) {
  __shared__ float tile[32][33];
  int t = threadIdx.x;
  int tx = t & 31, ty = t >> 5;          // ty in [0,8)
  int b = blockIdx.z;
  int n2t = blockIdx.x * 32, ct = blockIdx.y * 32;
#pragma unroll
  for (int i = 0; i < 4; ++i) {
    int c = ct + ty + i * 8;
    tile[ty + i * 8][tx] = f2[((size_t)b * 256 + c) * 2048 + n2t + tx];
  }
  __syncthreads();
#pragma unroll
  for (int i = 0; i < 4; ++i) {
    int n2 = n2t + ty + i * 8;
    f2t[((size_t)b * 2048 + n2) * 256 + ct + tx] = f2b(tile[tx][ty + i * 8]);
  }
}

// ---------------------------------------------------------------------------
// knn + interp + skip-copy. One block = one batch x 64 query points (1024 blk).
// Phase 1: each lane owns 2 queries (qg=t&31, q=qg+32i) and slice s=t>>5 of
// 256 candidates -> one ds_read_b128 feeds 128 (q,cand) pairs; the two
// half-waves read 2 distinct addresses (2-way broadcast = free).
// LDS ~45.6 KB -> 3 blocks/CU.  xb blocked: [panel][kt(12)][64n][32k] bf16.
// ---------------------------------------------------------------------------
__global__ __launch_bounds__(256) void knn_interp_kernel(
    const float* __restrict__ xyz1, const float* __restrict__ xyz2,
    const float* __restrict__ f1, const u16* __restrict__ f2t,
    u16* __restrict__ xb) {
  union Lds {
    struct { float4 pts[2048]; float md[8 * 64 * 3]; int mi[8 * 64 * 3]; } a;
    float f1t[128 * 65];
  };
  __shared__ Lds lds;
  __shared__ float wts[64 * 3];
  __shared__ int idxs[64 * 3];           // premultiplied by 256

  int t = threadIdx.x;
  int b = blockIdx.x >> 7;
  int n1_0 = (blockIdx.x & 127) * 64;
  int panel = blockIdx.x;

  // phase 0: stage candidates (x,y,z,|x|^2)
  const float* x2 = xyz2 + b * 3 * 2048;
  for (int j = t; j < 2048; j += 256) {
    float cx = x2[j], cy = x2[2048 + j], cz = x2[4096 + j];
    float nsq = (cx * cx + cy * cy) + cz * cz;
    lds.a.pts[j] = make_float4(cx, cy, cz, nsq);
  }
  __syncthreads();

  // phase 1: 8 slices x 256 candidates; 2 queries per lane
  {
    int qg = t & 31, s = t >> 5;
    const float* x1 = xyz1 + b * 3 * 8192;
    float nx[2], ny[2], nz[2], nsq1[2];
    float d[2][3];
    int id[2][3];
#pragma unroll
    for (int i = 0; i < 2; ++i) {
      int n1 = n1_0 + qg + 32 * i;
      float bx = x1[n1], by = x1[8192 + n1], bz = x1[16384 + n1];
      nsq1[i] = (bx * bx + by * by) + bz * bz;
      nx[i] = -2.f * bx; ny[i] = -2.f * by; nz[i] = -2.f * bz;
      d[i][0] = d[i][1] = d[i][2] = 3.4e38f;
      id[i][0] = id[i][1] = id[i][2] = 0;
    }
    int jb = s * 256;
#pragma unroll 4
    for (int jj = 0; jj < 256; ++jj) {
      float4 c = lds.a.pts[jb + jj];
      int j = jb + jj;
#pragma unroll
      for (int i = 0; i < 2; ++i) {
        float sq = fmaf(nx[i], c.x, fmaf(ny[i], c.y, fmaf(nz[i], c.z, nsq1[i] + c.w)));
        bool c0 = sq < d[i][0], c1 = sq < d[i][1], c2 = sq < d[i][2];
        id[i][2] = c1 ? id[i][1] : (c2 ? j : id[i][2]);
        id[i][1] = c0 ? id[i][0] : (c1 ? j : id[i][1]);
        id[i][0] = c0 ? j : id[i][0];
        d[i][2] = fminf(fmaxf(sq, d[i][1]), d[i][2]);   // med3
        d[i][1] = fminf(fmaxf(sq, d[i][0]), d[i][1]);   // med3
        d[i][0] = fminf(sq, d[i][0]);
      }
    }
#pragma unroll
    for (int i = 0; i < 2; ++i) {
      int q = qg + 32 * i;
#pragma unroll
      for (int k = 0; k < 3; ++k) {
        lds.a.md[(s * 64 + q) * 3 + k] = d[i][k];
        lds.a.mi[(s * 64 + q) * 3 + k] = id[i][k];
      }
    }
  }
  __syncthreads();
  if (t < 64) {
    // merge slices s=0..7 in ascending-index order (preserves tie-break)
    float d0 = 3.4e38f, d1 = 3.4e38f, d2 = 3.4e38f;
    int i0 = 0, i1 = 0, i2 = 0;
#pragma unroll
    for (int s = 0; s < 8; ++s) {
#pragma unroll
      for (int k = 0; k < 3; ++k) {
        float dd = lds.a.md[(s * 64 + t) * 3 + k];
        int ii = lds.a.mi[(s * 64 + t) * 3 + k];
        bool c0 = dd < d0, c1 = dd < d1, c2 = dd < d2;
        i2 = c1 ? i1 : (c2 ? ii : i2);
        i1 = c0 ? i0 : (c1 ? ii : i1);
        i0 = c0 ? ii : i0;
        d2 = fminf(fmaxf(dd, d1), d2);
        d1 = fminf(fmaxf(dd, d0), d1);
        d0 = fminf(dd, d0);
      }
    }
    float e0 = fmaxf(d0, 1e-10f), e1 = fmaxf(d1, 1e-10f), e2 = fmaxf(d2, 1e-10f);
    float w0 = 1.0f / e0, w1 = 1.0f / e1, w2 = 1.0f / e2;
    float sm = (w0 + w1) + w2;
    wts[t * 3 + 0] = w0 / sm; wts[t * 3 + 1] = w1 / sm; wts[t * 3 + 2] = w2 / sm;
    idxs[t * 3 + 0] = i0 * 256; idxs[t * 3 + 1] = i1 * 256; idxs[t * 3 + 2] = i2 * 256;
  }
  __syncthreads();

  // phase 2: interp 256 channels (thread = channel), write xb blocked
  {
    const u16* f2tb = f2t + (size_t)b * 2048 * 256;
    size_t xbase = (size_t)panel * 24576 + (size_t)((t >> 5) * 2048) + (t & 31);
#pragma unroll 4
    for (int p = 0; p < 64; ++p) {
      int j0 = idxs[p * 3 + 0], j1 = idxs[p * 3 + 1], j2 = idxs[p * 3 + 2];
      float w0 = wts[p * 3 + 0], w1 = wts[p * 3 + 1], w2 = wts[p * 3 + 2];
      float v = (w0 * b2f(f2tb[j0 + t]) + w1 * b2f(f2tb[j1 + t]))
                + w2 * b2f(f2tb[j2 + t]);
      xb[xbase + p * 32] = f2b(v);
    }
  }
  __syncthreads();   // before aliasing lds.a with lds.f1t

  // phase 3: skip features (channels 256..383) via LDS transpose
  {
    const float* f1b = f1 + (size_t)b * 128 * 8192 + n1_0;
    for (int it = 0; it < 32; ++it) {
      int c = it * 4 + (t >> 6);
      int n = t & 63;
      lds.f1t[c * 65 + n] = f1b[(size_t)c * 8192 + n];
    }
    __syncthreads();
    for (int it = 0; it < 32; ++it) {
      int v = it * 256 + t;
      int c = v & 127, p = v >> 7;
      float val = lds.f1t[c * 65 + p];
      xb[(size_t)panel * 24576 + (size_t)(8 + (c >> 5)) * 2048 + p * 32 + (c & 31)] = f2b(val);
    }
  }
}

// ---------------------------------------------------------------------------
// FUSED 2-layer GEMM. block = 1 panel (64 cols), 256 threads (4 waves),
// per-layer tile 256(o) x 64(n), mfma 16x16x32 bf16, streaming fragment loads.
// Layer 1: A=w1b[kt][256o][32k], B=xb[panel][kt(12)][64n][32k]  (global)
//   -> y1 tile kept in LDS, blocked [kt2(8)][64n][stride 40] bf16 (40 KB;
//      stride 40 keeps ushort4 writes / b128 reads at <=2-way bank aliasing).
// Layer 2: A=w2b[kt][256o][32k] (global, L2-hot), B=y1 tile (LDS)
//   -> BN+ReLU, f32 out [b][256][8192].
// Saves the 32MB+32MB y1 HBM round-trip of the 2-kernel version.
// ---------------------------------------------------------------------------
__global__ __launch_bounds__(256, 3) void gemm_fused_kernel(
    const u16* __restrict__ xin, const u16* __restrict__ w1b,
    const u16* __restrict__ w2b,
    const float* __restrict__ al1, const float* __restrict__ bt1,
    const float* __restrict__ al2, const float* __restrict__ bt2,
    float* __restrict__ fout) {
  __shared__ u16 y1t[8 * 64 * 40];       // 40960 B
  int t = threadIdx.x;
  int panel = blockIdx.x;
  int w = t >> 6, lane = t & 63, l15 = lane & 15, quad = lane >> 4;

  f32x4 acc[4][4];
#pragma unroll
  for (int m = 0; m < 4; ++m)
#pragma unroll
    for (int n = 0; n < 4; ++n)
      acc[m][n] = (f32x4){0.f, 0.f, 0.f, 0.f};

  // ---- layer 1 K-loop (KT=12) ----
  {
    const u16* aw = w1b + (size_t)(w * 64 + l15) * 32 + quad * 8;
    const u16* bx = xin + (size_t)panel * (12 * 2048) + (size_t)l15 * 32 + quad * 8;
#pragma unroll 2
    for (int kt = 0; kt < 12; ++kt) {
      short8 af[4], bf[4];
#pragma unroll
      for (int m = 0; m < 4; ++m)
        af[m] = *(const short8*)(aw + kt * 8192 + m * 512);
#pragma unroll
      for (int n = 0; n < 4; ++n)
        bf[n] = *(const short8*)(bx + kt * 2048 + n * 512);
#pragma unroll
      for (int m = 0; m < 4; ++m)
#pragma unroll
        for (int n = 0; n < 4; ++n)
          acc[m][n] = __builtin_amdgcn_mfma_f32_16x16x32_bf16(af[m], bf[n], acc[m][n], 0, 0, 0);
    }
  }

  // ---- epilogue 1: BN+ReLU -> bf16 -> LDS y1 tile (blocked, stride 40) ----
  {
    float al[4][4], bt[4][4];
#pragma unroll
    for (int m = 0; m < 4; ++m)
#pragma unroll
      for (int r = 0; r < 4; ++r) {
        int o = w * 64 + m * 16 + quad * 4 + r;
        al[m][r] = al1[o];
        bt[m][r] = bt1[o];
      }
#pragma unroll
    for (int m = 0; m < 4; ++m) {
      int kt2 = w * 2 + (m >> 1);
      int osub = (m & 1) * 16 + quad * 4;
#pragma unroll
      for (int n = 0; n < 4; ++n) {
        int col = n * 16 + l15;
        ushort4 pk;
        pk.x = f2b(fmaxf(fmaf(al[m][0], acc[m][n][0], bt[m][0]), 0.f));
        pk.y = f2b(fmaxf(fmaf(al[m][1], acc[m][n][1], bt[m][1]), 0.f));
        pk.z = f2b(fmaxf(fmaf(al[m][2], acc[m][n][2], bt[m][2]), 0.f));
        pk.w = f2b(fmaxf(fmaf(al[m][3], acc[m][n][3], bt[m][3]), 0.f));
        *(ushort4*)&y1t[(kt2 * 64 + col) * 40 + osub] = pk;
      }
    }
  }
  __syncthreads();

  // ---- layer 2 K-loop (KT=8): A global, B from LDS ----
#pragma unroll
  for (int m = 0; m < 4; ++m)
#pragma unroll
    for (int n = 0; n < 4; ++n)
      acc[m][n] = (f32x4){0.f, 0.f, 0.f, 0.f};
  {
    const u16* aw = w2b + (size_t)(w * 64 + l15) * 32 + quad * 8;
#pragma unroll 2
    for (int kt = 0; kt < 8; ++kt) {
      short8 af[4], bf[4];
#pragma unroll
      for (int m = 0; m < 4; ++m)
        af[m] = *(const short8*)(aw + kt * 8192 + m * 512);
#pragma unroll
      for (int n = 0; n < 4; ++n)
        bf[n] = *(const short8*)&y1t[(kt * 64 + n * 16 + l15) * 40 + quad * 8];
#pragma unroll
      for (int m = 0; m < 4; ++m)
#pragma unroll
        for (int n = 0; n < 4; ++n)
          acc[m][n] = __builtin_amdgcn_mfma_f32_16x16x32_bf16(af[m], bf[n], acc[m][n], 0, 0, 0);
    }
  }

  // ---- epilogue 2: BN+ReLU -> f32 out [b][256][8192] ----
  {
    float al[4][4], bt[4][4];
#pragma unroll
    for (int m = 0; m < 4; ++m)
#pragma unroll
      for (int r = 0; r < 4; ++r) {
        int o = w * 64 + m * 16 + quad * 4 + r;
        al[m][r] = al2[o];
        bt[m][r] = bt2[o];
      }
    int bb = panel >> 7;
    int n1base = (panel & 127) * 64;
#pragma unroll
    for (int m = 0; m < 4; ++m)
#pragma unroll
      for (int n = 0; n < 4; ++n) {
        int col = n * 16 + l15;
#pragma unroll
        for (int r = 0; r < 4; ++r) {
          int o = w * 64 + m * 16 + quad * 4 + r;
          float vv = fmaxf(fmaf(al[m][r], acc[m][n][r], bt[m][r]), 0.f);
          fout[(size_t)(bb * 256 + o) * 8192 + n1base + col] = vv;
        }
      }
  }
}

// ---------------------------------------------------------------------------
// ws layout (bytes):
//   [0,          50331648)  xb   bf16 [1024 panels][12][64][32]   48 MB
//   [50331648,   58720256)  f2t  bf16 [8][2048][256]               8 MB
//   [83886080,   84082688)  w1b  bf16 blocked
//   [84082688,   84213760)  w2b  bf16 blocked
//   [84213760,   84217856)  al1/bt1/al2/bt2 f32
// ---------------------------------------------------------------------------
extern "C" void kernel_launch(void* const* d_in, const int* in_sizes, int n_in,
                              void* d_out, int out_size, void* d_ws, size_t ws_size,
                              hipStream_t stream) {
  const float* xyz1 = (const float*)d_in[0];
  const float* xyz2 = (const float*)d_in[1];
  const float* f1   = (const float*)d_in[2];
  const float* f2   = (const float*)d_in[3];
  const float* w1   = (const float*)d_in[4];
  const float* b1   = (const float*)d_in[5];
  const float* g1   = (const float*)d_in[6];
  const float* be1  = (const float*)d_in[7];
  const float* m1   = (const float*)d_in[8];
  const float* v1   = (const float*)d_in[9];
  const float* w2   = (const float*)d_in[10];
  const float* b2   = (const float*)d_in[11];
  const float* g2   = (const float*)d_in[12];
  const float* be2  = (const float*)d_in[13];
  const float* m2   = (const float*)d_in[14];
  const float* v2   = (const float*)d_in[15];

  char* ws = (char*)d_ws;
  u16* xb   = (u16*)(ws);
  u16* f2t  = (u16*)(ws + 50331648);
  u16* w1b  = (u16*)(ws + 83886080);
  u16* w2b  = (u16*)(ws + 84082688);
  float* al1 = (float*)(ws + 84213760);
  float* bt1 = (float*)(ws + 84214784);
  float* al2 = (float*)(ws + 84215808);
  float* bt2 = (float*)(ws + 84216832);
  float* out = (float*)d_out;

  prep_kernel<<<642, 256, 0, stream>>>(w1, b1, g1, be1, m1, v1,
                                       w2, b2, g2, be2, m2, v2,
                                       w1b, w2b, al1, bt1, al2, bt2);
  transpose_f2_kernel<<<dim3(64, 8, 8), 256, 0, stream>>>(f2, f2t);
  knn_interp_kernel<<<1024, 256, 0, stream>>>(xyz1, xyz2, f1, f2t, xb);
  gemm_fused_kernel<<<1024, 256, 0, stream>>>(xb, w1b, w2b, al1, bt1, al2, bt2, out);
}

// Round 5
// 231.474 us; speedup vs baseline: 1.2835x; 1.1543x over previous
//
#include <hip/hip_runtime.h>
#include <hip/hip_bf16.h>

typedef unsigned short u16;
typedef __attribute__((ext_vector_type(4))) float f32x4;
typedef __attribute__((ext_vector_type(8))) short short8;

#define BN_EPS 1e-5f

__device__ __forceinline__ u16 f2b(float x) {
  union { float f; unsigned int u; } v; v.f = x;
  unsigned int r = (v.u + 0x7FFFu + ((v.u >> 16) & 1u)) >> 16;
  return (u16)r;
}
__device__ __forceinline__ float b2f(u16 u) {
  union { unsigned int u; float f; } v; v.u = ((unsigned int)u) << 16;
  return v.f;
}

// ---------------------------------------------------------------------------
// prep: fold BN into alpha/beta; convert W1/W2 to bf16 in blocked [kt][o][32k]
// ---------------------------------------------------------------------------
__global__ void prep_kernel(const float* __restrict__ w1, const float* __restrict__ b1,
                            const float* __restrict__ g1, const float* __restrict__ be1,
                            const float* __restrict__ m1, const float* __restrict__ v1,
                            const float* __restrict__ w2, const float* __restrict__ b2,
                            const float* __restrict__ g2, const float* __restrict__ be2,
                            const float* __restrict__ m2, const float* __restrict__ v2,
                            u16* __restrict__ w1b, u16* __restrict__ w2b,
                            float* __restrict__ al1, float* __restrict__ bt1,
                            float* __restrict__ al2, float* __restrict__ bt2) {
  int t = threadIdx.x;
  int blk = blockIdx.x;
  if (blk < 384) {                       // w1: 256x384
    int id = blk * 256 + t;
    unsigned o = (unsigned)id / 384u;
    unsigned c = (unsigned)id % 384u;
    w1b[(c >> 5) * 8192 + o * 32 + (c & 31)] = f2b(w1[id]);
  } else if (blk < 640) {                // w2: 256x256
    int j = (blk - 384) * 256 + t;
    unsigned o = (unsigned)j >> 8;
    unsigned c = (unsigned)j & 255u;
    w2b[(c >> 5) * 8192 + o * 32 + (c & 31)] = f2b(w2[j]);
  } else if (blk == 640) {
    float a = g1[t] / sqrtf(v1[t] + BN_EPS);
    al1[t] = a;
    bt1[t] = (b1[t] - m1[t]) * a + be1[t];
  } else {
    float a = g2[t] / sqrtf(v2[t] + BN_EPS);
    al2[t] = a;
    bt2[t] = (b2[t] - m2[t]) * a + be2[t];
  }
}

// ---------------------------------------------------------------------------
// transpose features2 [B][256][2048] f32 -> f2t [B][2048][256] bf16
// ---------------------------------------------------------------------------
__global__ void transpose_f2_kernel(const float* __restrict__ f2, u16* __restrict__ f2t) {
  __shared__ float tile[32][33];
  int t = threadIdx.x;
  int tx = t & 31, ty = t >> 5;          // ty in [0,8)
  int b = blockIdx.z;
  int n2t = blockIdx.x * 32, ct = blockIdx.y * 32;
#pragma unroll
  for (int i = 0; i < 4; ++i) {
    int c = ct + ty + i * 8;
    tile[ty + i * 8][tx] = f2[((size_t)b * 256 + c) * 2048 + n2t + tx];
  }
  __syncthreads();
#pragma unroll
  for (int i = 0; i < 4; ++i) {
    int n2 = n2t + ty + i * 8;
    f2t[((size_t)b * 2048 + n2) * 256 + ct + tx] = f2b(tile[tx][ty + i * 8]);
  }
}

// ---------------------------------------------------------------------------
// knn + interp + skip-copy — EXACT round-2 structure (best measured: 86 us,
// LDS 40448, VGPR ~56). lane = query (p=t&63), wave = slice (s=t>>6):
// all 64 lanes read the SAME pts[j] -> LDS broadcast, conflict-free.
// xb blocked layout: [panel][kt(12)][n(64)][kc(32)] bf16, panel = bn/64.
// ---------------------------------------------------------------------------
__global__ __launch_bounds__(256) void knn_interp_kernel(
    const float* __restrict__ xyz1, const float* __restrict__ xyz2,
    const float* __restrict__ f1, const u16* __restrict__ f2t,
    u16* __restrict__ xb) {
  union Lds {
    struct { float4 pts[2048]; float md[256 * 3]; int mi[256 * 3]; } a;
    float f1t[128 * 65];
  };
  __shared__ Lds lds;
  __shared__ float wts[64 * 3];
  __shared__ int idxs[64 * 3];           // premultiplied by 256

  int t = threadIdx.x;
  int b = blockIdx.x >> 7;
  int n1_0 = (blockIdx.x & 127) * 64;
  int panel = blockIdx.x;                // = b*128 + tile

  // phase 0: stage candidates (x,y,z,|x|^2)
  const float* x2 = xyz2 + b * 3 * 2048;
  for (int j = t; j < 2048; j += 256) {
    float cx = x2[j], cy = x2[2048 + j], cz = x2[4096 + j];
    float nsq = (cx * cx + cy * cy) + cz * cz;
    lds.a.pts[j] = make_float4(cx, cy, cz, nsq);
  }
  __syncthreads();

  // phase 1: sliced top-3; lane = query, wave = slice (broadcast LDS reads)
  {
    int p = t & 63, s = t >> 6;
    int n1 = n1_0 + p;
    const float* x1 = xyz1 + b * 3 * 8192;
    float bx = x1[n1], by = x1[8192 + n1], bz = x1[16384 + n1];
    float n1sq = (bx * bx + by * by) + bz * bz;
    float nx = -2.f * bx, ny = -2.f * by, nz = -2.f * bz;
    float d0 = 3.4e38f, d1 = 3.4e38f, d2 = 3.4e38f;
    int i0 = 0, i1 = 0, i2 = 0;
    int jb = s * 512;
#pragma unroll 4
    for (int jj = 0; jj < 512; ++jj) {
      float4 c = lds.a.pts[jb + jj];
      float sq = fmaf(nx, c.x, fmaf(ny, c.y, fmaf(nz, c.z, n1sq + c.w)));
      int j = jb + jj;
      bool c0 = sq < d0, c1 = sq < d1, c2 = sq < d2;
      d2 = c1 ? d1 : (c2 ? sq : d2);  i2 = c1 ? i1 : (c2 ? j : i2);
      d1 = c0 ? d0 : (c1 ? sq : d1); i1 = c0 ? i0 : (c1 ? j : i1);
      d0 = c0 ? sq : d0;             i0 = c0 ? j : i0;
    }
    lds.a.md[t * 3 + 0] = d0; lds.a.md[t * 3 + 1] = d1; lds.a.md[t * 3 + 2] = d2;
    lds.a.mi[t * 3 + 0] = i0; lds.a.mi[t * 3 + 1] = i1; lds.a.mi[t * 3 + 2] = i2;
  }
  __syncthreads();
  if (t < 64) {
    // merge slices s=0..3 in ascending-index order (preserves tie-break)
    float d0 = 3.4e38f, d1 = 3.4e38f, d2 = 3.4e38f;
    int i0 = 0, i1 = 0, i2 = 0;
#pragma unroll
    for (int s = 0; s < 4; ++s) {
#pragma unroll
      for (int k = 0; k < 3; ++k) {
        float d = lds.a.md[(s * 64 + t) * 3 + k];
        int i = lds.a.mi[(s * 64 + t) * 3 + k];
        bool c0 = d < d0, c1 = d < d1, c2 = d < d2;
        i2 = c1 ? i1 : (c2 ? i : i2);
        i1 = c0 ? i0 : (c1 ? i : i1);
        i0 = c0 ? i : i0;
        d2 = c1 ? d1 : (c2 ? d : d2);
        d1 = c0 ? d0 : (c1 ? d : d1);
        d0 = c0 ? d : d0;
      }
    }
    float e0 = fmaxf(d0, 1e-10f), e1 = fmaxf(d1, 1e-10f), e2 = fmaxf(d2, 1e-10f);
    float w0 = 1.0f / e0, w1 = 1.0f / e1, w2 = 1.0f / e2;
    float sm = (w0 + w1) + w2;
    wts[t * 3 + 0] = w0 / sm; wts[t * 3 + 1] = w1 / sm; wts[t * 3 + 2] = w2 / sm;
    idxs[t * 3 + 0] = i0 * 256; idxs[t * 3 + 1] = i1 * 256; idxs[t * 3 + 2] = i2 * 256;
  }
  __syncthreads();

  // phase 2: interp 256 channels (thread = channel), write xb blocked
  {
    const u16* f2tb = f2t + (size_t)b * 2048 * 256;
    size_t xbase = (size_t)panel * 24576 + (size_t)((t >> 5) * 2048) + (t & 31);
#pragma unroll 4
    for (int p = 0; p < 64; ++p) {
      int j0 = idxs[p * 3 + 0], j1 = idxs[p * 3 + 1], j2 = idxs[p * 3 + 2];
      float w0 = wts[p * 3 + 0], w1 = wts[p * 3 + 1], w2 = wts[p * 3 + 2];
      float v = (w0 * b2f(f2tb[j0 + t]) + w1 * b2f(f2tb[j1 + t]))
                + w2 * b2f(f2tb[j2 + t]);
      xb[xbase + p * 32] = f2b(v);
    }
  }
  __syncthreads();   // before aliasing lds.a with lds.f1t

  // phase 3: skip features (channels 256..383) via LDS transpose
  {
    const float* f1b = f1 + (size_t)b * 128 * 8192 + n1_0;
    for (int it = 0; it < 32; ++it) {
      int c = it * 4 + (t >> 6);
      int n = t & 63;
      lds.f1t[c * 65 + n] = f1b[(size_t)c * 8192 + n];
    }
    __syncthreads();
    for (int it = 0; it < 32; ++it) {
      int v = it * 256 + t;
      int c = v & 127, p = v >> 7;
      float val = lds.f1t[c * 65 + p];
      xb[(size_t)panel * 24576 + (size_t)(8 + (c >> 5)) * 2048 + p * 32 + (c & 31)] = f2b(val);
    }
  }
}

// ---------------------------------------------------------------------------
// FUSED 2-layer GEMM with explicit depth-1 register software pipeline.
// block = 1 panel (64 cols), 256 threads (4 waves), per-layer tile
// 256(o) x 64(n), mfma 16x16x32 bf16. K-loops have NO barriers; fragment
// loads for kt+1 are issued before kt's 16 MFMAs so the s_waitcnt for them
// lands after one full CU MFMA round (~600 cy) — covers L2/L3 latency.
// Layer 1: A=w1b (global, L2-hot), B=xb[panel] (global, L3)
//   -> y1 tile in LDS, blocked [kt2(8)][64n][stride 40] bf16 (40 KB).
// Layer 2: A=w2b (global), B=y1 tile (LDS) -> BN+ReLU -> f32 out.
// ---------------------------------------------------------------------------
__global__ __launch_bounds__(256) void gemm_fused_kernel(
    const u16* __restrict__ xin, const u16* __restrict__ w1b,
    const u16* __restrict__ w2b,
    const float* __restrict__ al1, const float* __restrict__ bt1,
    const float* __restrict__ al2, const float* __restrict__ bt2,
    float* __restrict__ fout) {
  __shared__ u16 y1t[8 * 64 * 40];       // 40960 B
  int t = threadIdx.x;
  int panel = blockIdx.x;
  int w = t >> 6, lane = t & 63, l15 = lane & 15, quad = lane >> 4;

  f32x4 acc[4][4];
#pragma unroll
  for (int m = 0; m < 4; ++m)
#pragma unroll
    for (int n = 0; n < 4; ++n)
      acc[m][n] = (f32x4){0.f, 0.f, 0.f, 0.f};

  // ---- layer 1 K-loop (KT=12), depth-1 register pipeline ----
  {
    const u16* aw = w1b + (size_t)(w * 64 + l15) * 32 + quad * 8;
    const u16* bx = xin + (size_t)panel * (12 * 2048) + (size_t)l15 * 32 + quad * 8;
    short8 af[2][4], bf[2][4];
#pragma unroll
    for (int m = 0; m < 4; ++m)
      af[0][m] = *(const short8*)(aw + m * 512);
#pragma unroll
    for (int n = 0; n < 4; ++n)
      bf[0][n] = *(const short8*)(bx + n * 512);
#pragma unroll
    for (int kt = 0; kt < 12; ++kt) {
      int cur = kt & 1, nxt = cur ^ 1;
      if (kt < 11) {
#pragma unroll
        for (int m = 0; m < 4; ++m)
          af[nxt][m] = *(const short8*)(aw + (kt + 1) * 8192 + m * 512);
#pragma unroll
        for (int n = 0; n < 4; ++n)
          bf[nxt][n] = *(const short8*)(bx + (kt + 1) * 2048 + n * 512);
      }
#pragma unroll
      for (int m = 0; m < 4; ++m)
#pragma unroll
        for (int n = 0; n < 4; ++n)
          acc[m][n] = __builtin_amdgcn_mfma_f32_16x16x32_bf16(af[cur][m], bf[cur][n], acc[m][n], 0, 0, 0);
    }
  }

  // ---- epilogue 1: BN+ReLU -> bf16 -> LDS y1 tile (blocked, stride 40) ----
  {
    float al[4][4], bt[4][4];
#pragma unroll
    for (int m = 0; m < 4; ++m)
#pragma unroll
      for (int r = 0; r < 4; ++r) {
        int o = w * 64 + m * 16 + quad * 4 + r;
        al[m][r] = al1[o];
        bt[m][r] = bt1[o];
      }
#pragma unroll
    for (int m = 0; m < 4; ++m) {
      int kt2 = w * 2 + (m >> 1);
      int osub = (m & 1) * 16 + quad * 4;
#pragma unroll
      for (int n = 0; n < 4; ++n) {
        int col = n * 16 + l15;
        ushort4 pk;
        pk.x = f2b(fmaxf(fmaf(al[m][0], acc[m][n][0], bt[m][0]), 0.f));
        pk.y = f2b(fmaxf(fmaf(al[m][1], acc[m][n][1], bt[m][1]), 0.f));
        pk.z = f2b(fmaxf(fmaf(al[m][2], acc[m][n][2], bt[m][2]), 0.f));
        pk.w = f2b(fmaxf(fmaf(al[m][3], acc[m][n][3], bt[m][3]), 0.f));
        *(ushort4*)&y1t[(kt2 * 64 + col) * 40 + osub] = pk;
      }
    }
  }
  __syncthreads();

  // ---- layer 2 K-loop (KT=8): A global (depth-1 pipeline), B from LDS ----
#pragma unroll
  for (int m = 0; m < 4; ++m)
#pragma unroll
    for (int n = 0; n < 4; ++n)
      acc[m][n] = (f32x4){0.f, 0.f, 0.f, 0.f};
  {
    const u16* aw = w2b + (size_t)(w * 64 + l15) * 32 + quad * 8;
    short8 af[2][4];
#pragma unroll
    for (int m = 0; m < 4; ++m)
      af[0][m] = *(const short8*)(aw + m * 512);
#pragma unroll
    for (int kt = 0; kt < 8; ++kt) {
      int cur = kt & 1, nxt = cur ^ 1;
      if (kt < 7) {
#pragma unroll
        for (int m = 0; m < 4; ++m)
          af[nxt][m] = *(const short8*)(aw + (kt + 1) * 8192 + m * 512);
      }
      short8 bf[4];
#pragma unroll
      for (int n = 0; n < 4; ++n)
        bf[n] = *(const short8*)&y1t[(kt * 64 + n * 16 + l15) * 40 + quad * 8];
#pragma unroll
      for (int m = 0; m < 4; ++m)
#pragma unroll
        for (int n = 0; n < 4; ++n)
          acc[m][n] = __builtin_amdgcn_mfma_f32_16x16x32_bf16(af[cur][m], bf[n], acc[m][n], 0, 0, 0);
    }
  }

  // ---- epilogue 2: BN+ReLU -> f32 out [b][256][8192] ----
  {
    float al[4][4], bt[4][4];
#pragma unroll
    for (int m = 0; m < 4; ++m)
#pragma unroll
      for (int r = 0; r < 4; ++r) {
        int o = w * 64 + m * 16 + quad * 4 + r;
        al[m][r] = al2[o];
        bt[m][r] = bt2[o];
      }
    int bb = panel >> 7;
    int n1base = (panel & 127) * 64;
#pragma unroll
    for (int m = 0; m < 4; ++m)
#pragma unroll
      for (int n = 0; n < 4; ++n) {
        int col = n * 16 + l15;
#pragma unroll
        for (int r = 0; r < 4; ++r) {
          int o = w * 64 + m * 16 + quad * 4 + r;
          float vv = fmaxf(fmaf(al[m][r], acc[m][n][r], bt[m][r]), 0.f);
          fout[(size_t)(bb * 256 + o) * 8192 + n1base + col] = vv;
        }
      }
  }
}

// ---------------------------------------------------------------------------
// ws layout (bytes):
//   [0,          50331648)  xb   bf16 [1024 panels][12][64][32]   48 MB
//   [50331648,   58720256)  f2t  bf16 [8][2048][256]               8 MB
//   [83886080,   84082688)  w1b  bf16 blocked
//   [84082688,   84213760)  w2b  bf16 blocked
//   [84213760,   84217856)  al1/bt1/al2/bt2 f32
// ---------------------------------------------------------------------------
extern "C" void kernel_launch(void* const* d_in, const int* in_sizes, int n_in,
                              void* d_out, int out_size, void* d_ws, size_t ws_size,
                              hipStream_t stream) {
  const float* xyz1 = (const float*)d_in[0];
  const float* xyz2 = (const float*)d_in[1];
  const float* f1   = (const float*)d_in[2];
  const float* f2   = (const float*)d_in[3];
  const float* w1   = (const float*)d_in[4];
  const float* b1   = (const float*)d_in[5];
  const float* g1   = (const float*)d_in[6];
  const float* be1  = (const float*)d_in[7];
  const float* m1   = (const float*)d_in[8];
  const float* v1   = (const float*)d_in[9];
  const float* w2   = (const float*)d_in[10];
  const float* b2   = (const float*)d_in[11];
  const float* g2   = (const float*)d_in[12];
  const float* be2  = (const float*)d_in[13];
  const float* m2   = (const float*)d_in[14];
  const float* v2   = (const float*)d_in[15];

  char* ws = (char*)d_ws;
  u16* xb   = (u16*)(ws);
  u16* f2t  = (u16*)(ws + 50331648);
  u16* w1b  = (u16*)(ws + 83886080);
  u16* w2b  = (u16*)(ws + 84082688);
  float* al1 = (float*)(ws + 84213760);
  float* bt1 = (float*)(ws + 84214784);
  float* al2 = (float*)(ws + 84215808);
  float* bt2 = (float*)(ws + 84216832);
  float* out = (float*)d_out;

  prep_kernel<<<642, 256, 0, stream>>>(w1, b1, g1, be1, m1, v1,
                                       w2, b2, g2, be2, m2, v2,
                                       w1b, w2b, al1, bt1, al2, bt2);
  transpose_f2_kernel<<<dim3(64, 8, 8), 256, 0, stream>>>(f2, f2t);
  knn_interp_kernel<<<1024, 256, 0, stream>>>(xyz1, xyz2, f1, f2t, xb);
  gemm_fused_kernel<<<1024, 256, 0, stream>>>(xb, w1b, w2b, al1, bt1, al2, bt2, out);
}